// Round 10
// baseline (117.840 us; speedup 1.0000x reference)
//
#include <hip/hip_runtime.h>

// RetinaNet target encoder for MI355X — round 10: wave-private compaction,
// register-broadcast GT boxes, and a MERGE-FREE per-GT reduce (lane-per-row
// scan, only one 2-step shfl per 16 rows).
// Inputs: bboxes [N,4] f32 xyxy, labels [N] i32, priors [M,4] f32 cxcywh.
// Outputs (concat): reg_targets [M,4] f32, cls_targets [M] (written as f32).
//
// N = 1024, M = 49104. Grid (192, 16): block = 256 priors x 64 GTs; all work
// per-wave (64 priors):
//   - wave bbox (butterfly) -> ballot mask of overlapping GTs (SGPR mask)
//   - per batch of T=16 active rows:
//       phase 1 (t = 0..15): jl = scalar ffs walk; GT box broadcast from
//         lane jl via v_readlane; IoU (exact reference op order) ->
//         per-prior argmax regs + tile[t][lane]
//       phase 2: lane (row=lane>>2, s=lane&3) scans tile[row][s*16..+15]
//         in ascending column (strict > == smallest m), then a 2-step
//         shfl_xor merge across the 4-lane group with explicit
//         (max iou, min m) tie-break; s==0 lane does one atomicMax ->
//         partG[gt]  (packed u64 = (iou_bits<<32) | (0xFFFFFFFF - m)).
// NO __syncthreads (tile slabs are wave-private; same-wave LDS RAW is
// ordered by compiler-inserted lgkmcnt waits).
//
// Exactness: skipped GT => GT box disjoint from the union bbox of the wave's
// 64 prior boxes => every pair intersection empty => clamped w or h == 0 =>
// iou == 0.0f bit-exactly in the reference too. Mask walk ascending j;
// strict-> argmax == numpy first-max. Packed u64 max == (max iou, smallest
// m). Padding rows repeat the first active row: equal values never displace
// a strict-> argmax; duplicate atomics write identical values. Every GT
// overlaps some level-7 prior with iou > 0, so partG zero-init never wins.
// Forced-assign duplicates: atomicMax(n) == numpy last-write-wins.

static constexpr float NEG_THRESH = 0.4f;
static constexpr float POS_THRESH = 0.5f;
static constexpr int N_GT = 1024;
static constexpr int GT_PER_BLK = 64;
static constexpr int NCHUNK = N_GT / GT_PER_BLK;   // 16
static constexpr int MPAD = 49152;                 // M rounded up to 256
static constexpr int BLK = 256;                    // priors per block (4 waves)
static constexpr int NB = MPAD / BLK;              // 192 prior blocks
static constexpr int T_ROWS = 16;                  // rows per batch
static constexpr int RSTRIDE = 69;                 // 69%32=5: writes & scans
                                                   // are exactly 2-way (free)

__device__ __forceinline__ float rdlane(float v, int sl) {
    return __uint_as_float(
        (unsigned)__builtin_amdgcn_readlane((int)__float_as_uint(v), sl));
}

// ---------------- Fused kernel ----------------
__global__ void __launch_bounds__(256) fused_kernel(
        const float* __restrict__ bboxes,
        const float* __restrict__ priors,
        float* __restrict__ part1iou,             // [NCHUNK][MPAD]
        unsigned short* __restrict__ part1idx,    // [NCHUNK][MPAD]
        unsigned long long* __restrict__ partG,   // [N_GT], pre-zeroed, atomicMax
        int* __restrict__ force_n,                // [M], init -1 (chunk 0)
        int M) {
#pragma clang fp contract(off)
    __shared__ float tile[4][T_ROWS][RSTRIDE];    // 17664 B -> 8 blocks/CU

    int tid = threadIdx.x;
    int lane = tid & 63;
    int wid = tid >> 6;
    int bx = blockIdx.x;
    int n0 = blockIdx.y * GT_PER_BLK;
    int m = bx * BLK + tid;
    bool valid = (m < M);

    float4 p = valid ? reinterpret_cast<const float4*>(priors)[m]
                     : make_float4(0.f, 0.f, 0.f, 0.f);
    float bx1 = p.x - p.z / 2.0f;
    float by1 = p.y - p.w / 2.0f;
    float bx2 = p.x + p.z / 2.0f;
    float by2 = p.y + p.w / 2.0f;
    float area_b = (bx2 - bx1) * (by2 - by1);

    // ---- wave bbox over its 64 priors ----
    float mnx = valid ? bx1 : 1e30f;
    float mny = valid ? by1 : 1e30f;
    float mxx = valid ? bx2 : -1e30f;
    float mxy = valid ? by2 : -1e30f;
#pragma unroll
    for (int mk = 1; mk < 64; mk <<= 1) {
        mnx = fminf(mnx, __shfl_xor(mnx, mk));
        mny = fminf(mny, __shfl_xor(mny, mk));
        mxx = fmaxf(mxx, __shfl_xor(mxx, mk));
        mxy = fmaxf(mxy, __shfl_xor(mxy, mk));
    }

    // ---- lane <-> GT: load chunk's GT boxes into registers, test, ballot ----
    float4 gt = reinterpret_cast<const float4*>(bboxes)[n0 + lane];
    float garea = (gt.z - gt.x) * (gt.w - gt.y);
    bool hit = (gt.x < mxx) & (gt.z > mnx) & (gt.y < mxy) & (gt.w > mny);
    unsigned long long rem = __ballot(hit);
    int cnt = __popcll(rem);

    float best = 0.0f;    // iou >= 0 everywhere; all-zero chunk -> (0, n0)
    int bestjr = n0;

    if (cnt > 0) {
        int j0 = __ffsll(rem) - 1;       // first active row (padding source)
        int row = lane >> 2;             // phase-2: 4 lanes per row
        int s = lane & 3;
        int wave_m0 = bx * BLK + wid * 64;
        int nbatches = (cnt + T_ROWS - 1) / T_ROWS;

        for (int b = 0; b < nbatches; ++b) {
            int myj = j0;   // GT row index this lane's group scans in phase 2
#pragma unroll
            for (int t = 0; t < T_ROWS; ++t) {
                int jl;
                if (rem) { jl = __ffsll(rem) - 1; rem &= rem - 1ull; }
                else     { jl = j0; }               // padding (duplicate row)

                // Broadcast GT box from lane jl — pure register traffic.
                float gx1 = rdlane(gt.x, jl);
                float gy1 = rdlane(gt.y, jl);
                float gx2 = rdlane(gt.z, jl);
                float gy2 = rdlane(gt.w, jl);
                float ga  = rdlane(garea, jl);

                // exact reference op order
                float ltx = fmaxf(gx1, bx1);
                float lty = fmaxf(gy1, by1);
                float rbx = fminf(gx2, bx2);
                float rby = fminf(gy2, by2);
                float w = rbx - ltx; if (w < 0.0f) w = 0.0f;
                float h = rby - lty; if (h < 0.0f) h = 0.0f;
                float inter = w * h;
                float iou = inter / (ga + area_b - inter);

                // per-prior argmax: strict > over ascending jl (mask order);
                // padding repeats an earlier value -> never displaces.
                if (iou > best) { best = iou; bestjr = n0 + jl; }
                tile[wid][t][lane] = valid ? iou : -1.0f;
                if (row == t) myj = jl;
            }

            // ---- phase 2: merge-free scan, 4 lanes per row ----
            float bi = -2.0f;
            int bm = 0;
#pragma unroll
            for (int c = 0; c < 16; ++c) {
                int col = s * 16 + c;               // ascending col per lane
                float v = tile[wid][row][col];
                if (v > bi) { bi = v; bm = col; }   // strict >: smallest col
            }
            // 2-step merge across the 4-lane group, exact (max, min-m)
#pragma unroll
            for (int msk = 1; msk < 4; msk <<= 1) {
                float oi = __shfl_xor(bi, msk);
                int om = __shfl_xor(bm, msk);
                if (oi > bi || (oi == bi && om < bm)) { bi = oi; bm = om; }
            }
            if (s == 0 && bi > 0.0f) {
                unsigned wm = (unsigned)(wave_m0 + bm);
                atomicMax(&partG[n0 + myj],
                          ((unsigned long long)__float_as_uint(bi) << 32) |
                          (unsigned long long)(0xFFFFFFFFu - wm));
            }
        }
    }

    if (valid) {
        size_t orow = (size_t)blockIdx.y * MPAD + m;
        part1iou[orow] = best;
        part1idx[orow] = (unsigned short)bestjr;
        if (blockIdx.y == 0) force_n[m] = -1;   // replay-safe init for rs
    }
}

// ---------------- RS: per-GT winner -> forced-assignment scatter -------------
__global__ void rs_kernel(const unsigned long long* __restrict__ partG,
                          int* __restrict__ force_n) {
    int n = blockIdx.x * blockDim.x + threadIdx.x;
    if (n >= N_GT) return;
    unsigned long long v = partG[n];
    int m = (int)(0xFFFFFFFFu - (unsigned)(v & 0xFFFFFFFFull));
    atomicMax(&force_n[m], n);   // duplicate priors: last write in np == max n
}

// ---------------- E: reduce per-prior partials + encode ----------------------
__global__ void __launch_bounds__(256) encode_kernel(
        const float* __restrict__ bboxes,
        const int* __restrict__ labels,
        const float* __restrict__ priors,
        const float* __restrict__ part1iou,
        const unsigned short* __restrict__ part1idx,
        const int* __restrict__ force_n,
        float* __restrict__ out, int M) {
#pragma clang fp contract(off)
    int m = blockIdx.x * 256 + threadIdx.x;
    if (m >= M) return;

    float bi = part1iou[m];
    int bn = part1idx[m];
    for (int c = 1; c < NCHUNK; ++c) {
        float v = part1iou[(size_t)c * MPAD + m];
        if (v > bi) { bi = v; bn = part1idx[(size_t)c * MPAD + m]; }
    }   // strict > ascending c == smallest n on ties (numpy first-max)

    float iou = bi;
    int mid = bn;
    int f = force_n[m];
    if (f >= 0) { mid = f; iou = POS_THRESH; }

    float4 g = reinterpret_cast<const float4*>(bboxes)[mid];
    float mcx = (g.x + g.z) / 2.0f;
    float mcy = (g.y + g.w) / 2.0f;
    float mw = g.z - g.x;
    float mh = g.w - g.y;

    float4 p = reinterpret_cast<const float4*>(priors)[m];
    float dcx = ((mcx - p.x) / p.z) / 0.1f;
    float dcy = ((mcy - p.y) / p.w) / 0.1f;
    float dw = logf(mw / p.z) / 0.2f;
    float dh = logf(mh / p.w) / 0.2f;

    reinterpret_cast<float4*>(out)[m] = make_float4(dcx, dcy, dw, dh);

    int cls = labels[mid];
    if (iou < POS_THRESH) cls = -1;
    if (iou < NEG_THRESH) cls = 0;
    out[(size_t)4 * M + m] = (float)cls;
}

extern "C" void kernel_launch(void* const* d_in, const int* in_sizes, int n_in,
                              void* d_out, int out_size, void* d_ws, size_t ws_size,
                              hipStream_t stream) {
    const float* bboxes = (const float*)d_in[0];
    const int* labels = (const int*)d_in[1];
    const float* priors = (const float*)d_in[2];
    int M = in_sizes[2] / 4;
    float* out = (float*)d_out;

    // Workspace (~4.9 MB): part1iou | part1idx | partG | force_n
    char* ws = (char*)d_ws;
    float* part1iou = (float*)ws;                                   // 3.15 MB
    unsigned short* part1idx =
        (unsigned short*)(ws + (size_t)NCHUNK * MPAD * 4);          // 1.57 MB
    unsigned long long* partG =
        (unsigned long long*)(ws + (size_t)NCHUNK * MPAD * 6);      // 8 KB
    int* force_n =
        (int*)(ws + (size_t)NCHUNK * MPAD * 6 + (size_t)N_GT * 8);  // 192 KB

    // partG must be 0 each call (atomicMax accumulator; replay-safe)
    hipMemsetAsync(partG, 0, (size_t)N_GT * 8, stream);

    fused_kernel<<<dim3(NB, NCHUNK), 256, 0, stream>>>(bboxes, priors, part1iou,
                                                       part1idx, partG, force_n, M);
    rs_kernel<<<(N_GT + 255) / 256, 256, 0, stream>>>(partG, force_n);
    encode_kernel<<<(MPAD + 255) / 256, 256, 0, stream>>>(bboxes, labels, priors,
                                                          part1iou, part1idx,
                                                          force_n, out, M);
}

// Round 11
// 38.378 us; speedup vs baseline: 3.0705x; 3.0705x over previous
//
#include <hip/hip_runtime.h>

// RetinaNet target encoder for MI355X — round 11: round-7 block-compaction
// structure with the three measured stalls fixed:
//   (1) heavy-first dispatch (levels 7..4 first) — kills straggler tail
//   (2) compacted GT data staged in LDS (incl. precomputed areas) — phase-1
//       rows are pure VALU + uniform LDS broadcasts, no VMEM/s_load in loop
//   (3) predicated tail batch (no padded duplicate-row IoU work)
//   (4) per-prior argmax reduced via global packed-u64 atomicMax (exact
//       (max iou, smallest n)) — no partial arrays, no encode scan
//
// Inputs: bboxes [N,4] f32 xyxy, labels [N] i32, priors [M,4] f32 cxcywh.
// Outputs (concat): reg_targets [M,4] f32, cls_targets [M] (written as f32).
//
// N = 1024, M = 49104. Grid (16 chunks, 192 prior-blocks reversed).
// Block = 256 priors x 64 GTs:
//   - block bbox over the 256 prior boxes (wave butterfly + LDS + barrier)
//   - wave 0 tests 64 GTs vs block bbox; failing GT => ALL pair-IoUs in this
//     block are exactly 0.0f in the reference (disjoint => clamped w/h == 0)
//     => skipping is bit-exact. ballot+prefix -> compacted, ascending list
//     of GT boxes+areas+indices in LDS.
//   - per 16-row batch: phase 1: IoU -> per-prior argmax regs + LDS tile;
//     phase 2: 16 lanes per row scan the tile transposed, 4-step shfl merge
//     with exact (max iou, min m) tie-break -> atomicMax partG[gt].
// Tie semantics == numpy everywhere: strict > over ascending index; packed
// u64 (iou_bits<<32)|(0xFFFFFFFF-idx) max == (max iou, smallest idx);
// forced-assign duplicates: atomicMax(n) == numpy last-write-wins.
// partG/part1 zero-init: any real write is > 0 (low half nonzero), and an
// all-zero chunk still writes (0, ~n0) to part1 so the global per-prior
// argmax over chunks picks the smallest n (= numpy argmax over zeros).

static constexpr float NEG_THRESH = 0.4f;
static constexpr float POS_THRESH = 0.5f;
static constexpr int N_GT = 1024;
static constexpr int GT_PER_BLK = 64;
static constexpr int NCHUNK = N_GT / GT_PER_BLK;   // 16
static constexpr int MPAD = 49152;                 // M rounded up to 256
static constexpr int BLK = 256;                    // priors per block
static constexpr int NB = MPAD / BLK;              // 192 prior blocks
static constexpr int T_ROWS = 16;                  // tile rows per batch
static constexpr int STRIDE = 264;                 // phase-1 write & phase-2
                                                   // scan both exactly 2-way

__device__ __forceinline__ unsigned long long packiou(float iou, unsigned idx_) {
    return ((unsigned long long)__float_as_uint(iou) << 32) |
           (unsigned long long)(0xFFFFFFFFu - idx_);
}

// ---------------- Fused kernel ----------------
__global__ void __launch_bounds__(256) fused_kernel(
        const float* __restrict__ bboxes,
        const float* __restrict__ priors,
        unsigned long long* __restrict__ part1,   // [MPAD] pre-zeroed, atomicMax
        unsigned long long* __restrict__ partG,   // [N_GT] pre-zeroed, atomicMax
        int* __restrict__ force_n,                // [M], init -1 (chunk 0)
        int M) {
#pragma clang fp contract(off)
    __shared__ float tile[T_ROWS][STRIDE];        // 16.9 KB
    __shared__ float sgx1[GT_PER_BLK], sgy1[GT_PER_BLK];
    __shared__ float sgx2[GT_PER_BLK], sgy2[GT_PER_BLK], sgar[GT_PER_BLK];
    __shared__ unsigned short sidx[GT_PER_BLK];
    __shared__ float sbb[4][4];
    __shared__ int scount;

    int tid = threadIdx.x;
    int lane = tid & 63;
    int wid = tid >> 6;
    int bx = (NB - 1) - blockIdx.y;               // heavy levels dispatch first
    int n0 = blockIdx.x * GT_PER_BLK;
    int m = bx * BLK + tid;
    bool valid = (m < M);

    float4 p = valid ? reinterpret_cast<const float4*>(priors)[m]
                     : make_float4(0.f, 0.f, 0.f, 0.f);
    float bx1 = p.x - p.z / 2.0f;
    float by1 = p.y - p.w / 2.0f;
    float bx2 = p.x + p.z / 2.0f;
    float by2 = p.y + p.w / 2.0f;
    float area_b = (bx2 - bx1) * (by2 - by1);

    // ---- block bbox over 256 prior boxes ----
    float mnx = valid ? bx1 : 1e30f;
    float mny = valid ? by1 : 1e30f;
    float mxx = valid ? bx2 : -1e30f;
    float mxy = valid ? by2 : -1e30f;
#pragma unroll
    for (int mk = 1; mk < 64; mk <<= 1) {
        mnx = fminf(mnx, __shfl_xor(mnx, mk));
        mny = fminf(mny, __shfl_xor(mny, mk));
        mxx = fmaxf(mxx, __shfl_xor(mxx, mk));
        mxy = fmaxf(mxy, __shfl_xor(mxy, mk));
    }
    if (lane == 0) {
        sbb[wid][0] = mnx; sbb[wid][1] = mny; sbb[wid][2] = mxx; sbb[wid][3] = mxy;
    }
    __syncthreads();

    // ---- wave 0: test 64 GTs, order-preserving compaction into LDS ----
    if (tid < 64) {
        float BX1 = fminf(fminf(sbb[0][0], sbb[1][0]), fminf(sbb[2][0], sbb[3][0]));
        float BY1 = fminf(fminf(sbb[0][1], sbb[1][1]), fminf(sbb[2][1], sbb[3][1]));
        float BX2 = fmaxf(fmaxf(sbb[0][2], sbb[1][2]), fmaxf(sbb[2][2], sbb[3][2]));
        float BY2 = fmaxf(fmaxf(sbb[0][3], sbb[1][3]), fmaxf(sbb[2][3], sbb[3][3]));
        float4 g = reinterpret_cast<const float4*>(bboxes)[n0 + tid];
        bool hit = (g.x < BX2) & (g.z > BX1) & (g.y < BY2) & (g.w > BY1);
        unsigned long long bal = __ballot(hit);
        if (hit) {
            int pos = __popcll(bal & ((1ull << tid) - 1ull));
            sgx1[pos] = g.x; sgy1[pos] = g.y;
            sgx2[pos] = g.z; sgy2[pos] = g.w;
            sgar[pos] = (g.z - g.x) * (g.w - g.y);   // area once per GT
            sidx[pos] = (unsigned short)tid;
        }
        if (tid == 0) scount = __popcll(bal);
    }
    __syncthreads();
    int cnt = scount;

    float best = 0.0f;    // iou >= 0 everywhere; all-zero chunk -> (0, n0)
    int bestn = n0;

    int row = tid >> 4;   // phase-2: 16 lanes per row
    int sub = tid & 15;
    int m0 = bx * BLK;

    int nfull = cnt >> 4;
    int tail = cnt & 15;

    for (int b = 0; b <= nfull; ++b) {
        int rows = (b < nfull) ? T_ROWS : tail;
        if (rows == 0) break;
        int base = b * T_ROWS;

        // ---- phase 1: straight-line IoU rows, LDS-broadcast GT data ----
#pragma unroll
        for (int r = 0; r < T_ROWS; ++r) {
            if (r < rows) {
                int idx = base + r;
                float gx1 = sgx1[idx], gy1 = sgy1[idx];
                float gx2 = sgx2[idx], gy2 = sgy2[idx];
                float ga  = sgar[idx];
                int   jn  = n0 + (int)sidx[idx];

                float ltx = fmaxf(gx1, bx1);
                float lty = fmaxf(gy1, by1);
                float rbx = fminf(gx2, bx2);
                float rby = fminf(gy2, by2);
                float w = rbx - ltx; if (w < 0.0f) w = 0.0f;
                float h = rby - lty; if (h < 0.0f) h = 0.0f;
                float inter = w * h;
                float iou = inter / (ga + area_b - inter);

                // strict > over ascending idx (list ascending) == first-max
                if (iou > best) { best = iou; bestn = jn; }
                tile[r][tid] = valid ? iou : -1.0f;
            } else {
                tile[r][tid] = -1.0f;    // predicated-off row: 1 store only
            }
        }
        __syncthreads();

        // ---- phase 2: per-GT argmax over this block's 256 priors ----
        float bi = -2.0f;
        int bm = 0;
#pragma unroll
        for (int k = 0; k < BLK / 16; ++k) {
            int col = sub + 16 * k;               // ascending col per lane
            float v = tile[row][col];
            if (v > bi) { bi = v; bm = col; }     // strict >: smallest col
        }
#pragma unroll
        for (int msk = 1; msk < 16; msk <<= 1) {  // 16-lane group merge
            float oi = __shfl_xor(bi, msk);
            int om = __shfl_xor(bm, msk);
            if (oi > bi || (oi == bi && om < bm)) { bi = oi; bm = om; }
        }
        if (sub == 0 && bi > 0.0f) {
            // bi > 0 => row < rows (dead rows are all -1) and winner is a
            // valid prior (invalid lanes wrote -1).
            int jr = (int)sidx[base + row];
            atomicMax(&partG[n0 + jr], packiou(bi, (unsigned)(m0 + bm)));
        }
        __syncthreads();   // tile reused next batch
    }

    if (valid) {
        atomicMax(&part1[m], packiou(best, (unsigned)bestn));
        if (blockIdx.x == 0) force_n[m] = -1;   // replay-safe init for rs
    }
}

// ---------------- RS: per-GT winner -> forced-assignment scatter -------------
__global__ void rs_kernel(const unsigned long long* __restrict__ partG,
                          int* __restrict__ force_n) {
    int n = blockIdx.x * blockDim.x + threadIdx.x;
    if (n >= N_GT) return;
    unsigned long long v = partG[n];
    int m = (int)(0xFFFFFFFFu - (unsigned)(v & 0xFFFFFFFFull));
    atomicMax(&force_n[m], n);   // duplicate priors: last write in np == max n
}

// ---------------- E: decode per-prior winner + encode ------------------------
__global__ void __launch_bounds__(256) encode_kernel(
        const float* __restrict__ bboxes,
        const int* __restrict__ labels,
        const float* __restrict__ priors,
        const unsigned long long* __restrict__ part1,
        const int* __restrict__ force_n,
        float* __restrict__ out, int M) {
#pragma clang fp contract(off)
    int m = blockIdx.x * 256 + threadIdx.x;
    if (m >= M) return;

    unsigned long long v = part1[m];
    float iou = __uint_as_float((unsigned)(v >> 32));
    int mid = (int)(0xFFFFFFFFu - (unsigned)(v & 0xFFFFFFFFull));

    int f = force_n[m];
    if (f >= 0) { mid = f; iou = POS_THRESH; }

    float4 g = reinterpret_cast<const float4*>(bboxes)[mid];
    float mcx = (g.x + g.z) / 2.0f;
    float mcy = (g.y + g.w) / 2.0f;
    float mw = g.z - g.x;
    float mh = g.w - g.y;

    float4 p = reinterpret_cast<const float4*>(priors)[m];
    float dcx = ((mcx - p.x) / p.z) / 0.1f;
    float dcy = ((mcy - p.y) / p.w) / 0.1f;
    float dw = logf(mw / p.z) / 0.2f;
    float dh = logf(mh / p.w) / 0.2f;

    reinterpret_cast<float4*>(out)[m] = make_float4(dcx, dcy, dw, dh);

    int cls = labels[mid];
    if (iou < POS_THRESH) cls = -1;
    if (iou < NEG_THRESH) cls = 0;
    out[(size_t)4 * M + m] = (float)cls;
}

extern "C" void kernel_launch(void* const* d_in, const int* in_sizes, int n_in,
                              void* d_out, int out_size, void* d_ws, size_t ws_size,
                              hipStream_t stream) {
    const float* bboxes = (const float*)d_in[0];
    const int* labels = (const int*)d_in[1];
    const float* priors = (const float*)d_in[2];
    int M = in_sizes[2] / 4;
    float* out = (float*)d_out;

    // Workspace (~0.6 MB): part1 [MPAD u64] | partG [N_GT u64] | force_n [MPAD int]
    char* ws = (char*)d_ws;
    unsigned long long* part1 = (unsigned long long*)ws;
    unsigned long long* partG = (unsigned long long*)(ws + (size_t)MPAD * 8);
    int* force_n = (int*)(ws + (size_t)MPAD * 8 + (size_t)N_GT * 8);

    // part1/partG are atomicMax accumulators: zero each call (replay-safe),
    // one contiguous memset.
    hipMemsetAsync(part1, 0, (size_t)(MPAD + N_GT) * 8, stream);

    fused_kernel<<<dim3(NCHUNK, NB), 256, 0, stream>>>(bboxes, priors, part1,
                                                       partG, force_n, M);
    rs_kernel<<<(N_GT + 255) / 256, 256, 0, stream>>>(partG, force_n);
    encode_kernel<<<(MPAD + 255) / 256, 256, 0, stream>>>(bboxes, labels, priors,
                                                          part1, force_n, out, M);
}

// Round 12
// 38.335 us; speedup vs baseline: 3.0739x; 1.0011x over previous
//
#include <hip/hip_runtime.h>

// RetinaNet target encoder for MI355X — round 12: round-11 structure, with
//   (1) custom init kernel instead of hipMemsetAsync (the rocclr fill showed
//       up as a ~39us dispatch) — also initializes force_n and encodes
//       part1's init as packed (iou=0, idx=0)
//   (2) per-prior atomicMax skipped when a chunk's best == 0 (init value
//       already encodes (0,0); packiou(0,n>=0) can never beat it) — prunes
//       most of the 786K u64 L2 atomics, bit-exactly.
//
// Inputs: bboxes [N,4] f32 xyxy, labels [N] i32, priors [M,4] f32 cxcywh.
// Outputs (concat): reg_targets [M,4] f32, cls_targets [M] (written as f32).
//
// N = 1024, M = 49104. Grid (16 chunks, 192 prior-blocks, heavy-first).
// Block = 256 priors x 64 GTs:
//   - block bbox over the 256 prior boxes (wave butterfly + LDS + barrier)
//   - wave 0 tests 64 GTs vs block bbox; failing GT => ALL pair-IoUs in this
//     block are exactly 0.0f in the reference (disjoint => clamped w/h == 0)
//     => skipping is bit-exact. ballot+prefix -> compacted ascending list of
//     GT boxes+areas+indices in LDS.
//   - per 16-row batch: phase 1: IoU -> per-prior argmax regs + LDS tile;
//     phase 2: 16 lanes per row scan the tile transposed, 4-step shfl merge
//     with exact (max iou, min m) tie-break -> atomicMax partG[gt].
// Tie semantics == numpy everywhere: strict > over ascending index; packed
// u64 (iou_bits<<32)|(0xFFFFFFFF-idx) max == (max iou, smallest idx);
// forced-assign duplicates: atomicMax(n) == numpy last-write-wins.

static constexpr float NEG_THRESH = 0.4f;
static constexpr float POS_THRESH = 0.5f;
static constexpr int N_GT = 1024;
static constexpr int GT_PER_BLK = 64;
static constexpr int NCHUNK = N_GT / GT_PER_BLK;   // 16
static constexpr int MPAD = 49152;                 // M rounded up to 256
static constexpr int BLK = 256;                    // priors per block
static constexpr int NB = MPAD / BLK;              // 192 prior blocks
static constexpr int T_ROWS = 16;                  // tile rows per batch
static constexpr int STRIDE = 264;                 // 2-way banks max (free)

__device__ __forceinline__ unsigned long long packiou(float iou, unsigned idx_) {
    return ((unsigned long long)__float_as_uint(iou) << 32) |
           (unsigned long long)(0xFFFFFFFFu - idx_);
}

// ---------------- Init: replaces hipMemsetAsync ------------------------------
__global__ void __launch_bounds__(256) init_kernel(
        unsigned long long* __restrict__ part1,
        unsigned long long* __restrict__ partG,
        int* __restrict__ force_n) {
    int i = blockIdx.x * 256 + threadIdx.x;
    part1[i] = 0x00000000FFFFFFFFull;   // packiou(0.0f, 0): numpy argmax of
    force_n[i] = -1;                    // an all-zero row is index 0
    if (i < N_GT) partG[i] = 0ull;
}

// ---------------- Fused kernel ----------------
__global__ void __launch_bounds__(256) fused_kernel(
        const float* __restrict__ bboxes,
        const float* __restrict__ priors,
        unsigned long long* __restrict__ part1,   // [MPAD] init packiou(0,0)
        unsigned long long* __restrict__ partG,   // [N_GT] init 0, atomicMax
        int M) {
#pragma clang fp contract(off)
    __shared__ float tile[T_ROWS][STRIDE];        // 16.9 KB
    __shared__ float sgx1[GT_PER_BLK], sgy1[GT_PER_BLK];
    __shared__ float sgx2[GT_PER_BLK], sgy2[GT_PER_BLK], sgar[GT_PER_BLK];
    __shared__ unsigned short sidx[GT_PER_BLK];
    __shared__ float sbb[4][4];
    __shared__ int scount;

    int tid = threadIdx.x;
    int lane = tid & 63;
    int wid = tid >> 6;
    int bx = (NB - 1) - blockIdx.y;               // heavy levels dispatch first
    int n0 = blockIdx.x * GT_PER_BLK;
    int m = bx * BLK + tid;
    bool valid = (m < M);

    float4 p = valid ? reinterpret_cast<const float4*>(priors)[m]
                     : make_float4(0.f, 0.f, 0.f, 0.f);
    float bx1 = p.x - p.z / 2.0f;
    float by1 = p.y - p.w / 2.0f;
    float bx2 = p.x + p.z / 2.0f;
    float by2 = p.y + p.w / 2.0f;
    float area_b = (bx2 - bx1) * (by2 - by1);

    // ---- block bbox over 256 prior boxes ----
    float mnx = valid ? bx1 : 1e30f;
    float mny = valid ? by1 : 1e30f;
    float mxx = valid ? bx2 : -1e30f;
    float mxy = valid ? by2 : -1e30f;
#pragma unroll
    for (int mk = 1; mk < 64; mk <<= 1) {
        mnx = fminf(mnx, __shfl_xor(mnx, mk));
        mny = fminf(mny, __shfl_xor(mny, mk));
        mxx = fmaxf(mxx, __shfl_xor(mxx, mk));
        mxy = fmaxf(mxy, __shfl_xor(mxy, mk));
    }
    if (lane == 0) {
        sbb[wid][0] = mnx; sbb[wid][1] = mny; sbb[wid][2] = mxx; sbb[wid][3] = mxy;
    }
    __syncthreads();

    // ---- wave 0: test 64 GTs, order-preserving compaction into LDS ----
    if (tid < 64) {
        float BX1 = fminf(fminf(sbb[0][0], sbb[1][0]), fminf(sbb[2][0], sbb[3][0]));
        float BY1 = fminf(fminf(sbb[0][1], sbb[1][1]), fminf(sbb[2][1], sbb[3][1]));
        float BX2 = fmaxf(fmaxf(sbb[0][2], sbb[1][2]), fmaxf(sbb[2][2], sbb[3][2]));
        float BY2 = fmaxf(fmaxf(sbb[0][3], sbb[1][3]), fmaxf(sbb[2][3], sbb[3][3]));
        float4 g = reinterpret_cast<const float4*>(bboxes)[n0 + tid];
        bool hit = (g.x < BX2) & (g.z > BX1) & (g.y < BY2) & (g.w > BY1);
        unsigned long long bal = __ballot(hit);
        if (hit) {
            int pos = __popcll(bal & ((1ull << tid) - 1ull));
            sgx1[pos] = g.x; sgy1[pos] = g.y;
            sgx2[pos] = g.z; sgy2[pos] = g.w;
            sgar[pos] = (g.z - g.x) * (g.w - g.y);   // area once per GT
            sidx[pos] = (unsigned short)tid;
        }
        if (tid == 0) scount = __popcll(bal);
    }
    __syncthreads();
    int cnt = scount;

    float best = 0.0f;    // iou >= 0 everywhere
    int bestn = n0;

    int row = tid >> 4;   // phase-2: 16 lanes per row
    int sub = tid & 15;
    int m0 = bx * BLK;

    int nfull = cnt >> 4;
    int tail = cnt & 15;

    for (int b = 0; b <= nfull; ++b) {
        int rows = (b < nfull) ? T_ROWS : tail;
        if (rows == 0) break;
        int base = b * T_ROWS;

        // ---- phase 1: straight-line IoU rows, LDS-broadcast GT data ----
#pragma unroll
        for (int r = 0; r < T_ROWS; ++r) {
            if (r < rows) {
                int idx = base + r;
                float gx1 = sgx1[idx], gy1 = sgy1[idx];
                float gx2 = sgx2[idx], gy2 = sgy2[idx];
                float ga  = sgar[idx];
                int   jn  = n0 + (int)sidx[idx];

                float ltx = fmaxf(gx1, bx1);
                float lty = fmaxf(gy1, by1);
                float rbx = fminf(gx2, bx2);
                float rby = fminf(gy2, by2);
                float w = rbx - ltx; if (w < 0.0f) w = 0.0f;
                float h = rby - lty; if (h < 0.0f) h = 0.0f;
                float inter = w * h;
                float iou = inter / (ga + area_b - inter);

                // strict > over ascending idx (list ascending) == first-max
                if (iou > best) { best = iou; bestn = jn; }
                tile[r][tid] = valid ? iou : -1.0f;
            } else {
                tile[r][tid] = -1.0f;    // predicated-off row: 1 store only
            }
        }
        __syncthreads();

        // ---- phase 2: per-GT argmax over this block's 256 priors ----
        float bi = -2.0f;
        int bm = 0;
#pragma unroll
        for (int k = 0; k < BLK / 16; ++k) {
            int col = sub + 16 * k;               // ascending col per lane
            float v = tile[row][col];
            if (v > bi) { bi = v; bm = col; }     // strict >: smallest col
        }
#pragma unroll
        for (int msk = 1; msk < 16; msk <<= 1) {  // 16-lane group merge
            float oi = __shfl_xor(bi, msk);
            int om = __shfl_xor(bm, msk);
            if (oi > bi || (oi == bi && om < bm)) { bi = oi; bm = om; }
        }
        if (sub == 0 && bi > 0.0f) {
            // bi > 0 => live row (dead rows all -1) and a valid winner prior
            int jr = (int)sidx[base + row];
            atomicMax(&partG[n0 + jr], packiou(bi, (unsigned)(m0 + bm)));
        }
        __syncthreads();   // tile reused next batch
    }

    // best == 0 chunks skip: init packiou(0,0) already >= packiou(0,n) for all
    // n >= 0, and decodes to numpy's argmax-over-zeros (index 0, iou 0).
    if (valid && best > 0.0f) {
        atomicMax(&part1[m], packiou(best, (unsigned)bestn));
    }
}

// ---------------- RS: per-GT winner -> forced-assignment scatter -------------
__global__ void rs_kernel(const unsigned long long* __restrict__ partG,
                          int* __restrict__ force_n) {
    int n = blockIdx.x * blockDim.x + threadIdx.x;
    if (n >= N_GT) return;
    unsigned long long v = partG[n];
    int m = (int)(0xFFFFFFFFu - (unsigned)(v & 0xFFFFFFFFull));
    atomicMax(&force_n[m], n);   // duplicate priors: last write in np == max n
}

// ---------------- E: decode per-prior winner + encode ------------------------
__global__ void __launch_bounds__(256) encode_kernel(
        const float* __restrict__ bboxes,
        const int* __restrict__ labels,
        const float* __restrict__ priors,
        const unsigned long long* __restrict__ part1,
        const int* __restrict__ force_n,
        float* __restrict__ out, int M) {
#pragma clang fp contract(off)
    int m = blockIdx.x * 256 + threadIdx.x;
    if (m >= M) return;

    unsigned long long v = part1[m];
    float iou = __uint_as_float((unsigned)(v >> 32));
    int mid = (int)(0xFFFFFFFFu - (unsigned)(v & 0xFFFFFFFFull));

    int f = force_n[m];
    if (f >= 0) { mid = f; iou = POS_THRESH; }

    float4 g = reinterpret_cast<const float4*>(bboxes)[mid];
    float mcx = (g.x + g.z) / 2.0f;
    float mcy = (g.y + g.w) / 2.0f;
    float mw = g.z - g.x;
    float mh = g.w - g.y;

    float4 p = reinterpret_cast<const float4*>(priors)[m];
    float dcx = ((mcx - p.x) / p.z) / 0.1f;
    float dcy = ((mcy - p.y) / p.w) / 0.1f;
    float dw = logf(mw / p.z) / 0.2f;
    float dh = logf(mh / p.w) / 0.2f;

    reinterpret_cast<float4*>(out)[m] = make_float4(dcx, dcy, dw, dh);

    int cls = labels[mid];
    if (iou < POS_THRESH) cls = -1;
    if (iou < NEG_THRESH) cls = 0;
    out[(size_t)4 * M + m] = (float)cls;
}

extern "C" void kernel_launch(void* const* d_in, const int* in_sizes, int n_in,
                              void* d_out, int out_size, void* d_ws, size_t ws_size,
                              hipStream_t stream) {
    const float* bboxes = (const float*)d_in[0];
    const int* labels = (const int*)d_in[1];
    const float* priors = (const float*)d_in[2];
    int M = in_sizes[2] / 4;
    float* out = (float*)d_out;

    // Workspace (~0.6 MB): part1 [MPAD u64] | partG [N_GT u64] | force_n [MPAD int]
    char* ws = (char*)d_ws;
    unsigned long long* part1 = (unsigned long long*)ws;
    unsigned long long* partG = (unsigned long long*)(ws + (size_t)MPAD * 8);
    int* force_n = (int*)(ws + (size_t)MPAD * 8 + (size_t)N_GT * 8);

    init_kernel<<<MPAD / 256, 256, 0, stream>>>(part1, partG, force_n);
    fused_kernel<<<dim3(NCHUNK, NB), 256, 0, stream>>>(bboxes, priors, part1,
                                                       partG, M);
    rs_kernel<<<(N_GT + 255) / 256, 256, 0, stream>>>(partG, force_n);
    encode_kernel<<<(MPAD + 255) / 256, 256, 0, stream>>>(bboxes, labels, priors,
                                                          part1, force_n, out, M);
}